// Round 3
// baseline (7513.964 us; speedup 1.0000x reference)
//
#include <hip/hip_runtime.h>
#include <cstdint>
#include <cstddef>

#define B_    16
#define ND_   4
#define H_    320
#define W_    480
#define P_    (H_ * W_)      // 153600
#define K_    32
#define CONF_ 0.9f
#define MARGIN_ 4.0f
#define MINC_ 15
#define MAXV  32768          // >> expected ~15.4k valid pixels/image
#define VSLACK 2048          // staging overread slack (records)
#define TILE_ 1024
#define NT_   (P_ / TILE_)   // 150 tiles per image
#define CHUNK_ 992           // records per LDS chunk; 992*32B = 31 KiB
#define CPAD_ 2              // pad records for unconditional prefetch reads

// ---------------------------------------------------------------------------
// 5-step DPP umin over lanes 0..31 -> broadcast via readlane(31).
// old = -1 (u32 max): disabled/invalid lanes never win the min.
// ---------------------------------------------------------------------------
__device__ __forceinline__ unsigned wave_umin32(unsigned v) {
  int x = (int)v, t;
  t = __builtin_amdgcn_update_dpp(-1, x, 0x111, 0xF, 0xF, false);  // row_shr:1
  x = ((unsigned)t < (unsigned)x) ? t : x;
  t = __builtin_amdgcn_update_dpp(-1, x, 0x112, 0xF, 0xF, false);  // row_shr:2
  x = ((unsigned)t < (unsigned)x) ? t : x;
  t = __builtin_amdgcn_update_dpp(-1, x, 0x114, 0xF, 0xF, false);  // row_shr:4
  x = ((unsigned)t < (unsigned)x) ? t : x;
  t = __builtin_amdgcn_update_dpp(-1, x, 0x118, 0xF, 0xF, false);  // row_shr:8
  x = ((unsigned)t < (unsigned)x) ? t : x;
  t = __builtin_amdgcn_update_dpp(-1, x, 0x142, 0xA, 0xF, false);  // row_bcast:15 -> row1
  x = ((unsigned)t < (unsigned)x) ? t : x;
  return (unsigned)__builtin_amdgcn_readlane(x, 31);               // min of lanes 0..31
}

// async global->LDS, 16B per lane, wave-uniform LDS base + lane*16 (guide §5)
__device__ __forceinline__ void gl_lds16(const void* g, void* l) {
  __builtin_amdgcn_global_load_lds(
      (const __attribute__((address_space(1))) unsigned*)g,
      (__attribute__((address_space(3))) unsigned*)l, 16, 0, 0);
}

// ---------------------------------------------------------------------------
// K1a: per-tile valid-pixel count. grid = B*NT blocks x 256 thr (4 px/thr).
// ---------------------------------------------------------------------------
__global__ __launch_bounds__(256) void count_kernel(
    const float* __restrict__ seg, unsigned* __restrict__ tileCnt) {
  const int bt = blockIdx.x;
  const int b = bt / NT_, t = bt % NT_;
  const int tid = threadIdx.x, w = tid >> 6, lane = tid & 63;
  const float4 s4 = ((const float4*)(seg + (size_t)b * P_ + (size_t)t * TILE_))[tid];
  int c = (s4.x >= CONF_) + (s4.y >= CONF_) + (s4.z >= CONF_) + (s4.w >= CONF_);
  #pragma unroll
  for (int o = 32; o > 0; o >>= 1) c += __shfl_down(c, o);
  __shared__ int sw[4];
  if (lane == 0) sw[w] = c;
  __syncthreads();
  if (tid == 0) tileCnt[bt] = (unsigned)(sw[0] + sw[1] + sw[2] + sw[3]);
}

// ---------------------------------------------------------------------------
// K1b: per-image exclusive scan of tile counts. grid = B blocks x 64.
// ---------------------------------------------------------------------------
__global__ __launch_bounds__(64) void scan_kernel(
    const unsigned* __restrict__ tileCnt, unsigned* __restrict__ tileOff,
    int* __restrict__ nv) {
  const int b = blockIdx.x, lane = threadIdx.x;
  unsigned carry = 0;
  for (int base = 0; base < NT_; base += 64) {
    const int t = base + lane;
    const unsigned v = (t < NT_) ? tileCnt[b * NT_ + t] : 0u;
    unsigned x = v;
    #pragma unroll
    for (int o = 1; o < 64; o <<= 1) {
      const unsigned u = __shfl_up(x, o);
      if (lane >= o) x += u;
    }
    if (t < NT_) tileOff[b * NT_ + t] = carry + x - v;
    carry += (unsigned)__shfl((int)x, 63);
  }
  if (lane == 0) nv[b] = (int)(carry < MAXV ? carry : MAXV);
}

// ---------------------------------------------------------------------------
// K1c: ordered scatter of valid-pixel records.
// Record: [e0 e1 e2 e3] [x_adj z rowf 0]
// ---------------------------------------------------------------------------
__global__ __launch_bounds__(256) void scatter_kernel(
    const float* __restrict__ seg, const float* __restrict__ emb,
    const float* __restrict__ offl, const float* __restrict__ hei,
    const unsigned* __restrict__ tileOff, float4* __restrict__ vdat) {
#pragma clang fp contract(off)
  const int bt = blockIdx.x;
  const int b = bt / NT_, t = bt % NT_;
  const int tid = threadIdx.x, w = tid >> 6, lane = tid & 63;
  const int p = t * TILE_ + tid * 4;                 // pixel index in image
  const size_t so = (size_t)b * P_;
  const float4 s4 = ((const float4*)(seg + so + (size_t)t * TILE_))[tid];
  const unsigned bits = (s4.x >= CONF_ ? 1u : 0u) | (s4.y >= CONF_ ? 2u : 0u) |
                        (s4.z >= CONF_ ? 4u : 0u) | (s4.w >= CONF_ ? 8u : 0u);
  const int c = __popc(bits);
  int x = c;
  #pragma unroll
  for (int o = 1; o < 64; o <<= 1) {
    const int u = __shfl_up(x, o);
    if (lane >= o) x += u;
  }
  const int excl = x - c;
  __shared__ int swt[4];
  if (lane == 63) swt[w] = x;
  __syncthreads();
  int wb = 0;
  #pragma unroll
  for (int j = 0; j < 4; ++j) wb += (j < w) ? swt[j] : 0;
  const unsigned sbase = tileOff[bt] + (unsigned)(wb + excl);

  if (bits) {
    const int pv = p >> 2;
    const float4 E0 = ((const float4*)(emb + ((size_t)b * ND_ + 0) * P_))[pv];
    const float4 E1 = ((const float4*)(emb + ((size_t)b * ND_ + 1) * P_))[pv];
    const float4 E2 = ((const float4*)(emb + ((size_t)b * ND_ + 2) * P_))[pv];
    const float4 E3 = ((const float4*)(emb + ((size_t)b * ND_ + 3) * P_))[pv];
    const float4 O4 = ((const float4*)(offl + so))[pv];
    const float4 Z4 = ((const float4*)(hei + so))[pv];
    const float e0a[4] = {E0.x, E0.y, E0.z, E0.w};
    const float e1a[4] = {E1.x, E1.y, E1.z, E1.w};
    const float e2a[4] = {E2.x, E2.y, E2.z, E2.w};
    const float e3a[4] = {E3.x, E3.y, E3.z, E3.w};
    const float oa[4]  = {O4.x, O4.y, O4.z, O4.w};
    const float za[4]  = {Z4.x, Z4.y, Z4.z, Z4.w};
    float4* vout = vdat + (size_t)b * (MAXV + VSLACK) * 2;
    int r = 0;
    #pragma unroll
    for (int j = 0; j < 4; ++j) {
      if (bits & (1u << j)) {
        const unsigned slot = sbase + (unsigned)r;
        ++r;
        if (slot < MAXV) {
          const float sg = 1.0f / (1.0f + expf(-oa[j]));
          const int pj = p + j;
          const float xadj = (float)(pj % W_) + sg;
          vout[(size_t)slot * 2 + 0] = make_float4(e0a[j], e1a[j], e2a[j], e3a[j]);
          vout[(size_t)slot * 2 + 1] = make_float4(xadj, za[j], (float)(pj / W_), 0.0f);
        }
      }
    }
  }
}

// ---------------------------------------------------------------------------
// K2: sequential greedy clustering — BRANCHLESS body, divisions off-chain.
// One wave per image; lane k<32 owns center k.
// ---------------------------------------------------------------------------
__global__ __launch_bounds__(64) void cluster_kernel(
    const float4* __restrict__ vdat, const int* __restrict__ nv,
    float* __restrict__ sumx, float* __restrict__ sumz,
    unsigned* __restrict__ cntb, int* __restrict__ ccount,
    float* __restrict__ dummy) {
#pragma clang fp contract(off)
  const int b = blockIdx.x;
  const int lane = threadIdx.x;
  const float4* vd = vdat + (size_t)b * (MAXV + VSLACK) * 2;
  const int n = nv[b];
  __shared__ float4 sld[2][(CHUNK_ + CPAD_) * 2];    // 2 x ~31.1 KiB

  float c0 = 0.f, c1 = 0.f, c2 = 0.f, c3 = 0.f;
  int cnt = 0, n_active = 0;
  float* sx = sumx + (size_t)b * K_ * H_;
  float* sz = sumz + (size_t)b * K_ * H_;
  unsigned* cb = cntb + (size_t)b * K_ * H_;
  float* dSx = dummy;               // shared dummy bins (rare no-op iterations)
  float* dSz = dummy + 1;
  unsigned* dCb = (unsigned*)(dummy + 2);

  const int nch = (n + CHUNK_ - 1) / CHUNK_;
  #define STAGE(s, c) do { \
      const char* g_ = (const char*)(vd + (size_t)(c) * CHUNK_ * 2) + (size_t)lane * 16; \
      char* l_ = (char*)&sld[(s)][0]; \
      _Pragma("unroll") \
      for (int j_ = 0; j_ < 31; ++j_) gl_lds16(g_ + j_ * 1024, l_ + j_ * 1024); \
    } while (0)

  if (nch > 0) STAGE(0, 0);
  for (int ch = 0; ch < nch; ++ch) {
    __syncthreads();                       // drains vmcnt: buf[ch&1] ready
    if (ch + 1 < nch) STAGE((ch + 1) & 1, ch + 1);   // prefetch next chunk
    const float4* rb = &sld[ch & 1][0];
    const int cn = (n - ch * CHUNK_ < CHUNK_) ? (n - ch * CHUNK_) : CHUNK_;

    // register prefetch depth 2 (pad records make unconditional reads safe)
    float4 A  = rb[0], Bv = rb[1];
    float4 A2 = rb[2], B2 = rb[3];
    for (int r = 0; r < cn; ++r) {
      const float4 A3 = rb[2 * (r + 2)];           // may be pad garbage: discarded
      const float4 B3 = rb[2 * (r + 2) + 1];

      const float e0 = A.x, e1 = A.y, e2 = A.z, e3 = A.w;
      const float xadj = Bv.x, zz = Bv.y;
      const int row = (int)Bv.z;

      // OFF-CHAIN: unconditional candidate center.
      // create case (cnt==0): (c*0 + e)/1 == e exactly (IEEE), so one formula
      // covers assign AND create. Divides overlap the distance/ladder chain.
      const float cf = (float)cnt;
      const float dn = cf + 1.0f;
      float t0 = c0 * cf; t0 = t0 + e0; const float n0 = t0 / dn;
      float t1 = c1 * cf; t1 = t1 + e1; const float n1 = t1 / dn;
      float t2 = c2 * cf; t2 = t2 + e2; const float n2 = t2 / dn;
      float t3 = c3 * cf; t3 = t3 + e3; const float n3 = t3 / dn;

      // CHAIN: distance, exact reference order sqrt(((q0+q1)+q2)+q3)
      float q0 = c0 - e0, q1 = c1 - e1, q2 = c2 - e2, q3 = c3 - e3;
      q0 *= q0; q1 *= q1; q2 *= q2; q3 *= q3;
      float s = q0 + q1; s = s + q2; s = s + q3;
      const float d = sqrtf(s);
      const unsigned db = (cnt > 0) ? __float_as_uint(d) : 0x7F800000u;

      const unsigned mb = wave_umin32(db);
      const unsigned long long eq = __ballot(db == mb);
      const int min_cid = __ffsll(eq) - 1;         // first-min tie-break
      const float min_dist = __uint_as_float(mb);

      const bool assign = (min_dist < MARGIN_);
      const bool grow = (n_active < K_);
      const bool do_ = assign || grow;
      const int upd = assign ? min_cid : (grow ? n_active : K_ - 1);

      // branchless apply
      const bool ap = do_ && (lane == upd);
      c0 = ap ? n0 : c0;  c1 = ap ? n1 : c1;
      c2 = ap ? n2 : c2;  c3 = ap ? n3 : c3;
      cnt += ap ? 1 : 0;

      if (lane == 0) {                              // off-chain, fire-and-forget
        const int idx = upd * H_ + row;
        float*    px = do_ ? (sx + idx) : dSx;
        float*    pz = do_ ? (sz + idx) : dSz;
        unsigned* pc = do_ ? (cb + idx) : dCb;
        atomicAdd(px, xadj);
        atomicAdd(pz, zz);
        atomicAdd(pc, 1u);
      }
      n_active += (!assign && grow) ? 1 : 0;
      A = A2; Bv = B2; A2 = A3; B2 = B3;
    }
  }
  if (lane < K_) ccount[b * K_ + lane] = cnt;
  #undef STAGE
}

// ---------------------------------------------------------------------------
// K3: per-(b,k) finalize: validity, means, BEV transform, H-flip.
// ---------------------------------------------------------------------------
__global__ __launch_bounds__(64) void finalize_kernel(
    const float* __restrict__ sumx, const float* __restrict__ sumz,
    const unsigned* __restrict__ cntb, const int* __restrict__ ccount,
    float* __restrict__ out) {
#pragma clang fp contract(off)
  const int bk = blockIdx.x;          // = b*K + k
  const int lane = threadIdx.x;
  const int cc = ccount[bk];
  const bool validc = (cc >= MINC_);
  const float* sx = sumx + (size_t)bk * H_;
  const float* sz = sumz + (size_t)bk * H_;
  const unsigned* cb = cntb + (size_t)bk * H_;

  unsigned cv[5];
  unsigned nh = 0;
  #pragma unroll
  for (int j = 0; j < 5; ++j) {
    const int h = j * 64 + lane;
    cv[j] = cb[h];
    nh += (unsigned)__popcll(__ballot(cv[j] > 0));   // uniform row count
  }
  const bool lane_ok = validc && (nh >= 2);

  float* pts  = out;
  float* mask = out + (size_t)B_ * K_ * H_ * 3;
  #pragma unroll
  for (int j = 0; j < 5; ++j) {
    const int h = j * 64 + lane;       // bin (pre-flip) row index
    const unsigned c = cv[j];
    const bool m = lane_ok && (c > 0);
    const int hh = H_ - 1 - h;         // output (flipped) row index
    const float denom = fmaxf((float)c, 1.0f);
    const float mx = sx[h] / denom;
    const float mz = sz[h] / denom;
    const float x = (float)(515 - h) * 0.2f;          // (MAX_X/MPP0 - h)*MPP0
    const float y = -(mx * 0.2f - 48.0f);             // -(mean_x*MPP1 - 240*MPP1)
    const size_t o = ((size_t)bk * H_ + hh) * 3;
    pts[o + 0] = m ? x : 0.0f;
    pts[o + 1] = m ? y : 0.0f;
    pts[o + 2] = m ? mz : 0.0f;
    mask[(size_t)bk * H_ + hh] = m ? 1.0f : 0.0f;
  }
}

// ---------------------------------------------------------------------------
extern "C" void kernel_launch(void* const* d_in, const int* in_sizes, int n_in,
                              void* d_out, int out_size, void* d_ws, size_t ws_size,
                              hipStream_t stream) {
  (void)in_sizes; (void)n_in; (void)out_size; (void)ws_size;
  const float* seg  = (const float*)d_in[0];
  const float* emb  = (const float*)d_in[1];
  const float* offl = (const float*)d_in[2];
  const float* hei  = (const float*)d_in[3];

  char* ws = (char*)d_ws;
  const size_t binsN = (size_t)B_ * K_ * H_;          // 163840
  float*    sumx    = (float*)ws;                                   // 655360
  float*    sumz    = (float*)(ws + binsN * 4);                     // 655360
  unsigned* cntb    = (unsigned*)(ws + binsN * 8);                  // 655360
  int*      ccount  = (int*)(ws + binsN * 12);                      // 2048
  int*      nv      = (int*)(ws + binsN * 12 + 2048);               // 64
  unsigned* tileCnt = (unsigned*)(ws + binsN * 12 + 2048 + 64);     // 9600
  unsigned* tileOff = (unsigned*)(ws + binsN * 12 + 2048 + 64 + 9600); // 9600
  float*    dummy   = (float*)(ws + binsN * 12 + 2048 + 64 + 9600 + 9600); // 256
  size_t voff = binsN * 12 + 2048 + 64 + 9600 + 9600 + 256;
  voff = (voff + 255) & ~(size_t)255;
  float4* vdat = (float4*)(ws + voff);    // 16*(MAXV+VSLACK)*32 B = 17.8 MB

  // zero the accumulation bins (ws is not re-poisoned between replays)
  hipMemsetAsync(ws, 0, binsN * 12, stream);

  count_kernel  <<<B_ * NT_, 256, 0, stream>>>(seg, tileCnt);
  scan_kernel   <<<B_,        64, 0, stream>>>(tileCnt, tileOff, nv);
  scatter_kernel<<<B_ * NT_, 256, 0, stream>>>(seg, emb, offl, hei, tileOff, vdat);
  cluster_kernel<<<B_,        64, 0, stream>>>(vdat, nv, sumx, sumz, cntb, ccount, dummy);
  finalize_kernel<<<B_ * K_,  64, 0, stream>>>(sumx, sumz, cntb, ccount, (float*)d_out);
}

// Round 4
// 5299.515 us; speedup vs baseline: 1.4179x; 1.4179x over previous
//
#include <hip/hip_runtime.h>
#include <cstdint>
#include <cstddef>

#define B_    16
#define ND_   4
#define H_    320
#define W_    480
#define P_    (H_ * W_)      // 153600
#define K_    32
#define CONF_ 0.9f
#define MARGIN_ 4.0f
#define MINC_ 15
#define MAXV  32768          // >> expected ~15.4k valid pixels/image
#define VSLACK 2048          // staging overread slack (records)
#define TILE_ 1024
#define NT_   (P_ / TILE_)   // 150 tiles per image
#define CHUNK_ 768           // records per LDS chunk; 768*32B = 24 KiB
#define INVALID_ 0xFFFFFFFFu

// ---------------------------------------------------------------------------
// 5-step DPP umin over lanes 0..31 -> broadcast via readlane(31).
// old = -1 (u32 max): boundary/invalid lanes never win the min.
// ---------------------------------------------------------------------------
__device__ __forceinline__ unsigned wave_umin32(unsigned v) {
  int x = (int)v, t;
  t = __builtin_amdgcn_update_dpp(-1, x, 0x111, 0xF, 0xF, false);  // row_shr:1
  x = ((unsigned)t < (unsigned)x) ? t : x;
  t = __builtin_amdgcn_update_dpp(-1, x, 0x112, 0xF, 0xF, false);  // row_shr:2
  x = ((unsigned)t < (unsigned)x) ? t : x;
  t = __builtin_amdgcn_update_dpp(-1, x, 0x114, 0xF, 0xF, false);  // row_shr:4
  x = ((unsigned)t < (unsigned)x) ? t : x;
  t = __builtin_amdgcn_update_dpp(-1, x, 0x118, 0xF, 0xF, false);  // row_shr:8
  x = ((unsigned)t < (unsigned)x) ? t : x;
  t = __builtin_amdgcn_update_dpp(-1, x, 0x142, 0xA, 0xF, false);  // row_bcast:15
  x = ((unsigned)t < (unsigned)x) ? t : x;
  return (unsigned)__builtin_amdgcn_readlane(x, 31);               // min of lanes 0..31
}

// async global->LDS, 16B per lane, wave-uniform LDS base + lane*16 (guide §5)
__device__ __forceinline__ void gl_lds16(const void* g, void* l) {
  __builtin_amdgcn_global_load_lds(
      (const __attribute__((address_space(1))) unsigned*)g,
      (__attribute__((address_space(3))) unsigned*)l, 16, 0, 0);
}

// ---------------------------------------------------------------------------
// K1a: per-tile valid-pixel count. grid = B*NT blocks x 256 thr (4 px/thr).
// ---------------------------------------------------------------------------
__global__ __launch_bounds__(256) void count_kernel(
    const float* __restrict__ seg, unsigned* __restrict__ tileCnt) {
  const int bt = blockIdx.x;
  const int b = bt / NT_, t = bt % NT_;
  const int tid = threadIdx.x, w = tid >> 6, lane = tid & 63;
  const float4 s4 = ((const float4*)(seg + (size_t)b * P_ + (size_t)t * TILE_))[tid];
  int c = (s4.x >= CONF_) + (s4.y >= CONF_) + (s4.z >= CONF_) + (s4.w >= CONF_);
  #pragma unroll
  for (int o = 32; o > 0; o >>= 1) c += __shfl_down(c, o);
  __shared__ int sw[4];
  if (lane == 0) sw[w] = c;
  __syncthreads();
  if (tid == 0) tileCnt[bt] = (unsigned)(sw[0] + sw[1] + sw[2] + sw[3]);
}

// ---------------------------------------------------------------------------
// K1b: per-image exclusive scan of tile counts. grid = B blocks x 64.
// ---------------------------------------------------------------------------
__global__ __launch_bounds__(64) void scan_kernel(
    const unsigned* __restrict__ tileCnt, unsigned* __restrict__ tileOff,
    int* __restrict__ nv) {
  const int b = blockIdx.x, lane = threadIdx.x;
  unsigned carry = 0;
  for (int base = 0; base < NT_; base += 64) {
    const int t = base + lane;
    const unsigned v = (t < NT_) ? tileCnt[b * NT_ + t] : 0u;
    unsigned x = v;
    #pragma unroll
    for (int o = 1; o < 64; o <<= 1) {
      const unsigned u = __shfl_up(x, o);
      if (lane >= o) x += u;
    }
    if (t < NT_) tileOff[b * NT_ + t] = carry + x - v;
    carry += (unsigned)__shfl((int)x, 63);
  }
  if (lane == 0) nv[b] = (int)(carry < MAXV ? carry : MAXV);
}

// ---------------------------------------------------------------------------
// K1c: ordered scatter of valid-pixel records.
// Record: [e0 e1 e2 e3] [x_adj z rowf 0]
// ---------------------------------------------------------------------------
__global__ __launch_bounds__(256) void scatter_kernel(
    const float* __restrict__ seg, const float* __restrict__ emb,
    const float* __restrict__ offl, const float* __restrict__ hei,
    const unsigned* __restrict__ tileOff, float4* __restrict__ vdat) {
#pragma clang fp contract(off)
  const int bt = blockIdx.x;
  const int b = bt / NT_, t = bt % NT_;
  const int tid = threadIdx.x, w = tid >> 6, lane = tid & 63;
  const int p = t * TILE_ + tid * 4;                 // pixel index in image
  const size_t so = (size_t)b * P_;
  const float4 s4 = ((const float4*)(seg + so + (size_t)t * TILE_))[tid];
  const unsigned bits = (s4.x >= CONF_ ? 1u : 0u) | (s4.y >= CONF_ ? 2u : 0u) |
                        (s4.z >= CONF_ ? 4u : 0u) | (s4.w >= CONF_ ? 8u : 0u);
  const int c = __popc(bits);
  int x = c;
  #pragma unroll
  for (int o = 1; o < 64; o <<= 1) {
    const int u = __shfl_up(x, o);
    if (lane >= o) x += u;
  }
  const int excl = x - c;
  __shared__ int swt[4];
  if (lane == 63) swt[w] = x;
  __syncthreads();
  int wb = 0;
  #pragma unroll
  for (int j = 0; j < 4; ++j) wb += (j < w) ? swt[j] : 0;
  const unsigned sbase = tileOff[bt] + (unsigned)(wb + excl);

  if (bits) {
    const int pv = p >> 2;
    const float4 E0 = ((const float4*)(emb + ((size_t)b * ND_ + 0) * P_))[pv];
    const float4 E1 = ((const float4*)(emb + ((size_t)b * ND_ + 1) * P_))[pv];
    const float4 E2 = ((const float4*)(emb + ((size_t)b * ND_ + 2) * P_))[pv];
    const float4 E3 = ((const float4*)(emb + ((size_t)b * ND_ + 3) * P_))[pv];
    const float4 O4 = ((const float4*)(offl + so))[pv];
    const float4 Z4 = ((const float4*)(hei + so))[pv];
    const float e0a[4] = {E0.x, E0.y, E0.z, E0.w};
    const float e1a[4] = {E1.x, E1.y, E1.z, E1.w};
    const float e2a[4] = {E2.x, E2.y, E2.z, E2.w};
    const float e3a[4] = {E3.x, E3.y, E3.z, E3.w};
    const float oa[4]  = {O4.x, O4.y, O4.z, O4.w};
    const float za[4]  = {Z4.x, Z4.y, Z4.z, Z4.w};
    float4* vout = vdat + (size_t)b * (MAXV + VSLACK) * 2;
    int r = 0;
    #pragma unroll
    for (int j = 0; j < 4; ++j) {
      if (bits & (1u << j)) {
        const unsigned slot = sbase + (unsigned)r;
        ++r;
        if (slot < MAXV) {
          const float sg = 1.0f / (1.0f + expf(-oa[j]));
          const int pj = p + j;
          const float xadj = (float)(pj % W_) + sg;
          vout[(size_t)slot * 2 + 0] = make_float4(e0a[j], e1a[j], e2a[j], e3a[j]);
          vout[(size_t)slot * 2 + 1] = make_float4(xadj, za[j], (float)(pj / W_), 0.0f);
        }
      }
    }
  }
}

// ---------------------------------------------------------------------------
// K2: sequential greedy clustering. One wave per image; lane k<32 owns
// center k. ZERO vmem in the inner loop: records come from LDS (staged via
// global_load_lds), bin updates go to an LDS queue (lane-0 ds_write) that is
// drained by all 64 lanes at chunk boundaries (atomics latency-hidden there).
// ---------------------------------------------------------------------------
__global__ __launch_bounds__(64) void cluster_kernel(
    const float4* __restrict__ vdat, const int* __restrict__ nv,
    float* __restrict__ sumx, float* __restrict__ sumz,
    unsigned* __restrict__ cntb, int* __restrict__ ccount,
    float* __restrict__ dummy) {
#pragma clang fp contract(off)
  const int b = blockIdx.x;
  const int lane = threadIdx.x;
  const float4* vd = vdat + (size_t)b * (MAXV + VSLACK) * 2;
  const int n = nv[b];
  __shared__ float4 sld[2][CHUNK_ * 2 + 4];   // 2 x ~24 KiB (+pad for prefetch)
  __shared__ float4 q[CHUNK_];                // 12 KiB update queue

  float c0 = 0.f, c1 = 0.f, c2 = 0.f, c3 = 0.f;
  int cnt = 0, n_active = 0;
  float* sx = sumx + (size_t)b * K_ * H_;
  float* sz = sumz + (size_t)b * K_ * H_;
  unsigned* cb = cntb + (size_t)b * K_ * H_;
  float* dSx = dummy;               // dummy bins for predicated-off drain slots
  float* dSz = dummy + 1;
  unsigned* dCb = (unsigned*)(dummy + 2);

  const int nch = (n + CHUNK_ - 1) / CHUNK_;
  // stage chunk c into buffer s: 768 records = 24 KiB = 24 x 1 KiB rows
  #define STAGE(s, c) do { \
      const char* g_ = (const char*)(vd + (size_t)(c) * CHUNK_ * 2) + (size_t)lane * 16; \
      char* l_ = (char*)&sld[(s)][0]; \
      _Pragma("unroll") \
      for (int j_ = 0; j_ < 24; ++j_) gl_lds16(g_ + j_ * 1024, l_ + j_ * 1024); \
    } while (0)

  if (nch > 0) STAGE(0, 0);
  for (int ch = 0; ch < nch; ++ch) {
    __syncthreads();                       // drains vmcnt: buf[ch&1] ready
    if (ch + 1 < nch) STAGE((ch + 1) & 1, ch + 1);   // prefetch next chunk
    const float4* rb = &sld[ch & 1][0];
    const int cn = (n - ch * CHUNK_ < CHUNK_) ? (n - ch * CHUNK_) : CHUNK_;

    // register prefetch depth 2 (pad slots make unconditional reads safe)
    float4 A  = rb[0], Bv = rb[1];
    float4 A2 = rb[2], B2 = rb[3];
    for (int r = 0; r < cn; ++r) {
      const float4 A3 = rb[2 * (r + 2)];   // may be pad garbage: discarded
      const float4 B3 = rb[2 * (r + 2) + 1];

      const float e0 = A.x, e1 = A.y, e2 = A.z, e3 = A.w;
      const float xadj = Bv.x, zz = Bv.y;
      const int row = (int)Bv.z;

      // OFF-CHAIN: unconditional candidate center.
      // create case (cnt==0): (c*0 + e)/1 == e exactly (IEEE), one formula
      // covers assign AND create; divides overlap the distance/ladder chain.
      const float cf = (float)cnt;
      const float dn = cf + 1.0f;
      float t0 = c0 * cf; t0 = t0 + e0; const float n0 = t0 / dn;
      float t1 = c1 * cf; t1 = t1 + e1; const float n1 = t1 / dn;
      float t2 = c2 * cf; t2 = t2 + e2; const float n2 = t2 / dn;
      float t3 = c3 * cf; t3 = t3 + e3; const float n3 = t3 / dn;

      // CHAIN: distance, exact reference order sqrt(((q0+q1)+q2)+q3)
      float q0 = c0 - e0, q1 = c1 - e1, q2 = c2 - e2, q3 = c3 - e3;
      q0 *= q0; q1 *= q1; q2 *= q2; q3 *= q3;
      float s = q0 + q1; s = s + q2; s = s + q3;
      const float d = sqrtf(s);
      const unsigned db = (cnt > 0) ? __float_as_uint(d) : 0x7F800000u;

      const unsigned mb = wave_umin32(db);
      const unsigned long long eq = __ballot(db == mb);
      const int min_cid = __ffsll(eq) - 1;         // first-min tie-break
      const float min_dist = __uint_as_float(mb);

      const bool assign = (min_dist < MARGIN_);
      const bool grow = (n_active < K_);
      const bool do_ = assign || grow;
      const int upd = assign ? min_cid : (grow ? n_active : K_ - 1);

      // branchless apply
      const bool ap = do_ && (lane == upd);
      c0 = ap ? n0 : c0;  c1 = ap ? n1 : c1;
      c2 = ap ? n2 : c2;  c3 = ap ? n3 : c3;
      cnt += ap ? 1 : 0;

      // enqueue bin update (LDS only; lgkm domain, never waited here)
      if (lane == 0) {
        const unsigned idx = do_ ? (unsigned)(upd * H_ + row) : INVALID_;
        q[r] = make_float4(xadj, zz, __uint_as_float(idx), 0.0f);
      }
      n_active += (!assign && grow) ? 1 : 0;
      A = A2; Bv = B2; A2 = A3; B2 = B3;
    }

    // drain queue: 64 lanes, atomics latency-hidden across lanes/slots
    const int ng = (cn + 63) >> 6;
    for (int g = 0; g < ng; ++g) {
      const int j = g * 64 + lane;
      const float4 e = q[(j < cn) ? j : 0];
      const unsigned idx = __float_as_uint(e.z);
      const bool ok = (j < cn) && (idx != INVALID_);
      float*    px = ok ? (sx + idx) : dSx;
      float*    pz = ok ? (sz + idx) : dSz;
      unsigned* pc = ok ? (cb + idx) : dCb;
      atomicAdd(px, e.x);
      atomicAdd(pz, e.y);
      atomicAdd(pc, 1u);
    }
  }
  if (lane < K_) ccount[b * K_ + lane] = cnt;
  #undef STAGE
}

// ---------------------------------------------------------------------------
// K3: per-(b,k) finalize: validity, means, BEV transform, H-flip.
// ---------------------------------------------------------------------------
__global__ __launch_bounds__(64) void finalize_kernel(
    const float* __restrict__ sumx, const float* __restrict__ sumz,
    const unsigned* __restrict__ cntb, const int* __restrict__ ccount,
    float* __restrict__ out) {
#pragma clang fp contract(off)
  const int bk = blockIdx.x;          // = b*K + k
  const int lane = threadIdx.x;
  const int cc = ccount[bk];
  const bool validc = (cc >= MINC_);
  const float* sx = sumx + (size_t)bk * H_;
  const float* sz = sumz + (size_t)bk * H_;
  const unsigned* cb = cntb + (size_t)bk * H_;

  unsigned cv[5];
  unsigned nh = 0;
  #pragma unroll
  for (int j = 0; j < 5; ++j) {
    const int h = j * 64 + lane;
    cv[j] = cb[h];
    nh += (unsigned)__popcll(__ballot(cv[j] > 0));   // uniform row count
  }
  const bool lane_ok = validc && (nh >= 2);

  float* pts  = out;
  float* mask = out + (size_t)B_ * K_ * H_ * 3;
  #pragma unroll
  for (int j = 0; j < 5; ++j) {
    const int h = j * 64 + lane;       // bin (pre-flip) row index
    const unsigned c = cv[j];
    const bool m = lane_ok && (c > 0);
    const int hh = H_ - 1 - h;         // output (flipped) row index
    const float denom = fmaxf((float)c, 1.0f);
    const float mx = sx[h] / denom;
    const float mz = sz[h] / denom;
    const float x = (float)(515 - h) * 0.2f;          // (MAX_X/MPP0 - h)*MPP0
    const float y = -(mx * 0.2f - 48.0f);             // -(mean_x*MPP1 - 240*MPP1)
    const size_t o = ((size_t)bk * H_ + hh) * 3;
    pts[o + 0] = m ? x : 0.0f;
    pts[o + 1] = m ? y : 0.0f;
    pts[o + 2] = m ? mz : 0.0f;
    mask[(size_t)bk * H_ + hh] = m ? 1.0f : 0.0f;
  }
}

// ---------------------------------------------------------------------------
extern "C" void kernel_launch(void* const* d_in, const int* in_sizes, int n_in,
                              void* d_out, int out_size, void* d_ws, size_t ws_size,
                              hipStream_t stream) {
  (void)in_sizes; (void)n_in; (void)out_size; (void)ws_size;
  const float* seg  = (const float*)d_in[0];
  const float* emb  = (const float*)d_in[1];
  const float* offl = (const float*)d_in[2];
  const float* hei  = (const float*)d_in[3];

  char* ws = (char*)d_ws;
  const size_t binsN = (size_t)B_ * K_ * H_;          // 163840
  float*    sumx    = (float*)ws;                                   // 655360
  float*    sumz    = (float*)(ws + binsN * 4);                     // 655360
  unsigned* cntb    = (unsigned*)(ws + binsN * 8);                  // 655360
  int*      ccount  = (int*)(ws + binsN * 12);                      // 2048
  int*      nv      = (int*)(ws + binsN * 12 + 2048);               // 64
  unsigned* tileCnt = (unsigned*)(ws + binsN * 12 + 2048 + 64);     // 9600
  unsigned* tileOff = (unsigned*)(ws + binsN * 12 + 2048 + 64 + 9600); // 9600
  float*    dummy   = (float*)(ws + binsN * 12 + 2048 + 64 + 9600 + 9600); // 256
  size_t voff = binsN * 12 + 2048 + 64 + 9600 + 9600 + 256;
  voff = (voff + 255) & ~(size_t)255;
  float4* vdat = (float4*)(ws + voff);    // 16*(MAXV+VSLACK)*32 B = 17.8 MB

  // zero the accumulation bins (ws is not re-poisoned between replays)
  hipMemsetAsync(ws, 0, binsN * 12, stream);

  count_kernel  <<<B_ * NT_, 256, 0, stream>>>(seg, tileCnt);
  scan_kernel   <<<B_,        64, 0, stream>>>(tileCnt, tileOff, nv);
  scatter_kernel<<<B_ * NT_, 256, 0, stream>>>(seg, emb, offl, hei, tileOff, vdat);
  cluster_kernel<<<B_,        64, 0, stream>>>(vdat, nv, sumx, sumz, cntb, ccount, dummy);
  finalize_kernel<<<B_ * K_,  64, 0, stream>>>(sumx, sumz, cntb, ccount, (float*)d_out);
}